// Round 3
// baseline (293.272 us; speedup 1.0000x reference)
//
#include <hip/hip_runtime.h>
#include <hip/hip_bf16.h>

#define BB   32768
#define LL   1024
#define FEA  1028
#define MEM  50
#define DATE 32

typedef float  f32x4  __attribute__((ext_vector_type(4)));
typedef __bf16 bf16x8 __attribute__((ext_vector_type(8)));

__device__ __forceinline__ float wave_max(float v) {
    #pragma unroll
    for (int off = 32; off; off >>= 1) v = fmaxf(v, __shfl_xor(v, off));
    return v;
}
__device__ __forceinline__ float wave_sum(float v) {
    #pragma unroll
    for (int off = 32; off; off >>= 1) v += __shfl_xor(v, off);
    return v;
}
// tanh via __expf: exact at both saturations, ~1e-6 abs error in between.
__device__ __forceinline__ float fast_tanh(float v) {
    float e = __expf(2.f * v);
    return 1.f - 2.f / (e + 1.f);
}

// ---------------- K1: read-streaming kernel -------------------------------
// blocks [0, 2048): weight/bias GEMV over x (16 rows/block, 4 rows/wave).
//   Pure read stream: 16 independent 1KB loads in flight per wave, one
//   interleaved butterfly pair, fast tanh, 2 scalar stores per row.
// blocks [2048, 2304): fold transposed-conv into memory matrix:
//   wc[n*64+k] = sum_j convt_w[j] * mem_W[k][n+4-j], zero-padded k in [50,64)
__global__ __launch_bounds__(256) void prep_and_wb(
        const float* __restrict__ convt_w,
        const float* __restrict__ mem_W,
        const float* __restrict__ x,
        const float* __restrict__ fcw_w, const float* __restrict__ fcw_b,
        const float* __restrict__ fcb_w, const float* __restrict__ fcb_b,
        __bf16* __restrict__ wc,
        float* __restrict__ out) {
    if (blockIdx.x >= 2048) {
        int idx = (blockIdx.x - 2048) * 256 + threadIdx.x;   // 65536
        int n = idx >> 6, k = idx & 63;
        float acc = 0.f;
        if (k < MEM) {
            #pragma unroll
            for (int j = 0; j < 5; ++j)
                acc += convt_w[j] * mem_W[k * FEA + n + 4 - j];
        }
        wc[n * 64 + k] = (__bf16)acc;
        return;
    }

    const int lane = threadIdx.x & 63;
    const int wid  = threadIdx.x >> 6;
    const int b0   = blockIdx.x * 16;

    f32x4 wv[4], bv[4];
    #pragma unroll
    for (int c = 0; c < 4; ++c) {
        wv[c] = *(const f32x4*)(fcw_w + c * 256 + lane * 4);
        bv[c] = *(const f32x4*)(fcb_w + c * 256 + lane * 4);
    }
    f32x4 xv[4][4];
    #pragma unroll
    for (int rr = 0; rr < 4; ++rr)
        #pragma unroll
        for (int c = 0; c < 4; ++c)
            xv[rr][c] = *(const f32x4*)(x + (size_t)(b0 + wid * 4 + rr) * LL
                                          + c * 256 + lane * 4);
    float fwb = fcw_b[0], fbb = fcb_b[0];
    #pragma unroll
    for (int rr = 0; rr < 4; ++rr) {
        int r = wid * 4 + rr;
        float aw = 0.f, ab = 0.f;
        #pragma unroll
        for (int c = 0; c < 4; ++c)
            #pragma unroll
            for (int j = 0; j < 4; ++j) {
                aw += xv[rr][c][j] * wv[c][j];
                ab += xv[rr][c][j] * bv[c][j];
            }
        #pragma unroll
        for (int off = 1; off <= 32; off <<= 1) {
            aw += __shfl_xor(aw, off);
            ab += __shfl_xor(ab, off);
        }
        if (lane == 0) {
            out[(size_t)BB * LL + (b0 + r)]      = fast_tanh(aw + fwb) * 0.5f + 1.0f;
            out[(size_t)BB * LL + BB + (b0 + r)] = fast_tanh(ab + fbb) * 0.5f;
        }
    }
}

// ---------------- K2: write-streaming kernel -------------------------------
// att softmax -> MFMA against folded wc -> LDS-staged row-contiguous stores.
// Reads only dv/dW/wc/w/b (all small or L2-hot); writes the 134 MB out tensor.
// Round 3: NORMAL stores (round-2 nontemporal stores suspected of throttling
// the streaming-store path; the harness fill hits 6.7 TB/s with cached stores).
__global__ __launch_bounds__(256) void memconv_main(
        const float* __restrict__ dv,
        const float* __restrict__ dW,
        const __bf16* __restrict__ wc,
        float* __restrict__ out) {
    __shared__ __bf16 att_s[16 * 72];          // [row][k], 144B stride
    __shared__ float  w_s[16], b_s[16];
    __shared__ float  stage[4][16 * 72];       // per-wave D staging

    const int lane = threadIdx.x & 63;
    const int wid  = threadIdx.x >> 6;
    const int cg   = lane & 15;
    const int kg   = lane >> 4;
    const int b0   = blockIdx.x * 16;

    // w/b readback for this block's 16 rows (written by prep_and_wb)
    if (threadIdx.x < 16) {
        w_s[threadIdx.x] = out[(size_t)BB * LL + b0 + threadIdx.x];
        b_s[threadIdx.x] = out[(size_t)BB * LL + BB + b0 + threadIdx.x];
    }

    // ---- Phase 0: att for rows wid*4 .. wid*4+3 ----
    {
        int m = lane < MEM ? lane : MEM - 1;
        float dwv[DATE];
        const f32x4* dwp = (const f32x4*)(dW + m * DATE);
        #pragma unroll
        for (int c = 0; c < 8; ++c) {
            f32x4 v = dwp[c];
            #pragma unroll
            for (int j = 0; j < 4; ++j) dwv[c * 4 + j] = v[j];
        }
        #pragma unroll
        for (int rr = 0; rr < 4; ++rr) {
            int r = wid * 4 + rr;
            const f32x4* dvp = (const f32x4*)(dv + (size_t)(b0 + r) * DATE);
            float sc = 0.f;
            #pragma unroll
            for (int c = 0; c < 8; ++c) {
                f32x4 v = dvp[c];
                #pragma unroll
                for (int j = 0; j < 4; ++j) sc += v[j] * dwv[c * 4 + j];
            }
            float scm = (lane < MEM) ? sc : -1e30f;
            float mx  = wave_max(scm);
            float e   = (lane < MEM) ? __expf(sc - mx) : 0.f;
            float s   = wave_sum(e);
            float p   = e / s;
            float d   = p - 0.0025f;
            float p2  = (d > 0.f) ? p * d / (d + 1e-12f) : 0.f;
            float s2  = wave_sum(p2) + 1e-12f;
            float att = p2 / s2;
            att_s[r * 72 + lane] = (lane < MEM) ? (__bf16)att : (__bf16)0.f;
        }
    }
    __syncthreads();

    // ---- Phase B: transposed-operand MFMA + LDS-staged contiguous stores ----
    // A = wc (m = n-dim), B = att (col = batch). D[n kg*4+j][batch cg].
    {
        bf16x8 bfr0 = *(const bf16x8*)(att_s + cg * 72 + kg * 8);
        bf16x8 bfr1 = *(const bf16x8*)(att_s + cg * 72 + 32 + kg * 8);
        float* st = stage[wid];
        const int n0 = wid * 256;
        #pragma unroll
        for (int R = 0; R < 4; ++R) {
            // compute 4 tiles (64 n-columns), stage D into LDS
            #pragma unroll
            for (int t = 0; t < 4; ++t) {
                int n = n0 + (R * 4 + t) * 16 + cg;
                bf16x8 a0 = *(const bf16x8*)(wc + n * 64 + kg * 8);
                bf16x8 a1 = *(const bf16x8*)(wc + n * 64 + 32 + kg * 8);
                f32x4 acc = {0.f, 0.f, 0.f, 0.f};
                acc = __builtin_amdgcn_mfma_f32_16x16x32_bf16(a0, bfr0, acc, 0, 0, 0);
                acc = __builtin_amdgcn_mfma_f32_16x16x32_bf16(a1, bfr1, acc, 0, 0, 0);
                *(f32x4*)(st + cg * 72 + t * 16 + kg * 4) = acc;
            }
            // flush: row-contiguous, 4x 256B segments per inst, cached stores
            #pragma unroll
            for (int j = 0; j < 4; ++j) {
                int row = j * 4 + (lane >> 4);
                int nl  = (lane & 15) * 4;
                f32x4 v = *(const f32x4*)(st + row * 72 + nl);
                float w = w_s[row], bi = b_s[row];
                f32x4 o;
                #pragma unroll
                for (int k = 0; k < 4; ++k) o[k] = v[k] * w + bi;
                *(f32x4*)(out + (size_t)(b0 + row) * LL + n0 + R * 64 + nl) = o;
            }
        }
    }
}

extern "C" void kernel_launch(void* const* d_in, const int* in_sizes, int n_in,
                              void* d_out, int out_size, void* d_ws, size_t ws_size,
                              hipStream_t stream) {
    const float* x     = (const float*)d_in[0];
    const float* dv    = (const float*)d_in[1];
    // d_in[2] = conv_w: DEAD CODE in the reference (st is overwritten by st_mem)
    const float* convt = (const float*)d_in[3];
    const float* memW  = (const float*)d_in[4];
    const float* dateW = (const float*)d_in[5];
    const float* fcww  = (const float*)d_in[6];
    const float* fcwb  = (const float*)d_in[7];
    const float* fcbw  = (const float*)d_in[8];
    const float* fcbb  = (const float*)d_in[9];
    float* out = (float*)d_out;
    __bf16* wc = (__bf16*)d_ws;   // 64K bf16 = 128 KB

    prep_and_wb <<<2304,    256, 0, stream>>>(convt, memW, x, fcww, fcwb, fcbw, fcbb, wc, out);
    memconv_main<<<BB / 16, 256, 0, stream>>>(dv, dateW, wc, out);
}

// Round 4
// 284.676 us; speedup vs baseline: 1.0302x; 1.0302x over previous
//
#include <hip/hip_runtime.h>
#include <hip/hip_bf16.h>

#define BB   32768
#define LL   1024
#define FEA  1028
#define MEM  50
#define DATE 32

typedef float  f32x4  __attribute__((ext_vector_type(4)));
typedef __bf16 bf16x8 __attribute__((ext_vector_type(8)));

__device__ __forceinline__ float wave_max(float v) {
    #pragma unroll
    for (int off = 32; off; off >>= 1) v = fmaxf(v, __shfl_xor(v, off));
    return v;
}
__device__ __forceinline__ float wave_sum(float v) {
    #pragma unroll
    for (int off = 32; off; off >>= 1) v += __shfl_xor(v, off);
    return v;
}
// tanh via __expf: exact at both saturations, ~1e-6 abs error in between.
__device__ __forceinline__ float fast_tanh(float v) {
    float e = __expf(2.f * v);
    return 1.f - 2.f / (e + 1.f);
}

// ---------------- K1: reads + small products -------------------------------
// blocks [0, 2048):    wb GEMV over x (16 rows/block) -> out tail  [read stream]
// blocks [2048, 4096): att softmax (16 rows/block) -> att_g bf16[32768][64]
// blocks [4096, 4352): wc[n*64+k] = sum_j convt_w[j]*mem_W[k][n+4-j]
__global__ __launch_bounds__(256) void prep_and_wb(
        const float* __restrict__ convt_w,
        const float* __restrict__ mem_W,
        const float* __restrict__ x,
        const float* __restrict__ fcw_w, const float* __restrict__ fcw_b,
        const float* __restrict__ fcb_w, const float* __restrict__ fcb_b,
        const float* __restrict__ dv,
        const float* __restrict__ dW,
        __bf16* __restrict__ wc,
        __bf16* __restrict__ att_g,
        float* __restrict__ out) {
    const int lane = threadIdx.x & 63;
    const int wid  = threadIdx.x >> 6;

    if (blockIdx.x >= 4096) {              // ---- wc prep ----
        int idx = (blockIdx.x - 4096) * 256 + threadIdx.x;   // 65536
        int n = idx >> 6, k = idx & 63;
        float acc = 0.f;
        if (k < MEM) {
            #pragma unroll
            for (int j = 0; j < 5; ++j)
                acc += convt_w[j] * mem_W[k * FEA + n + 4 - j];
        }
        wc[n * 64 + k] = (__bf16)acc;
        return;
    }

    if (blockIdx.x >= 2048) {              // ---- att softmax ----
        const int b0 = (blockIdx.x - 2048) * 16;
        int m = lane < MEM ? lane : MEM - 1;
        float dwv[DATE];
        const f32x4* dwp = (const f32x4*)(dW + m * DATE);
        #pragma unroll
        for (int c = 0; c < 8; ++c) {
            f32x4 v = dwp[c];
            #pragma unroll
            for (int j = 0; j < 4; ++j) dwv[c * 4 + j] = v[j];
        }
        #pragma unroll
        for (int rr = 0; rr < 4; ++rr) {
            int r = b0 + wid * 4 + rr;
            const f32x4* dvp = (const f32x4*)(dv + (size_t)r * DATE);
            float sc = 0.f;
            #pragma unroll
            for (int c = 0; c < 8; ++c) {
                f32x4 v = dvp[c];
                #pragma unroll
                for (int j = 0; j < 4; ++j) sc += v[j] * dwv[c * 4 + j];
            }
            float scm = (lane < MEM) ? sc : -1e30f;
            float mx  = wave_max(scm);
            float e   = (lane < MEM) ? __expf(sc - mx) : 0.f;
            float s   = wave_sum(e);
            float p   = e / s;
            float d   = p - 0.0025f;
            float p2  = (d > 0.f) ? p * d / (d + 1e-12f) : 0.f;
            float s2  = wave_sum(p2) + 1e-12f;
            float att = p2 / s2;
            att_g[(size_t)r * 64 + lane] = (lane < MEM) ? (__bf16)att : (__bf16)0.f;
        }
        return;
    }

    // ---- wb GEMV: 16 rows/block, 4 rows/wave, full-row contiguous loads ----
    const int b0 = blockIdx.x * 16;
    f32x4 wv[4], bv[4];
    #pragma unroll
    for (int c = 0; c < 4; ++c) {
        wv[c] = *(const f32x4*)(fcw_w + c * 256 + lane * 4);
        bv[c] = *(const f32x4*)(fcb_w + c * 256 + lane * 4);
    }
    f32x4 xv[4][4];
    #pragma unroll
    for (int rr = 0; rr < 4; ++rr)
        #pragma unroll
        for (int c = 0; c < 4; ++c)
            xv[rr][c] = *(const f32x4*)(x + (size_t)(b0 + wid * 4 + rr) * LL
                                          + c * 256 + lane * 4);
    float fwb = fcw_b[0], fbb = fcb_b[0];
    #pragma unroll
    for (int rr = 0; rr < 4; ++rr) {
        int r = wid * 4 + rr;
        float aw = 0.f, ab = 0.f;
        #pragma unroll
        for (int c = 0; c < 4; ++c)
            #pragma unroll
            for (int j = 0; j < 4; ++j) {
                aw += xv[rr][c][j] * wv[c][j];
                ab += xv[rr][c][j] * bv[c][j];
            }
        #pragma unroll
        for (int off = 1; off <= 32; off <<= 1) {
            aw += __shfl_xor(aw, off);
            ab += __shfl_xor(ab, off);
        }
        if (lane == 0) {
            out[(size_t)BB * LL + (b0 + r)]      = fast_tanh(aw + fwb) * 0.5f + 1.0f;
            out[(size_t)BB * LL + BB + (b0 + r)] = fast_tanh(ab + fbb) * 0.5f;
        }
    }
}

// ---------------- K2: barrier-free per-wave store engine -------------------
// Each WAVE independently owns 16 batch rows x 512 n:
//   rg = wid&1 -> rows r0 = blockIdx.x*32 + rg*16;  nh = wid>>1 -> n0 = nh*512.
// Loads att B-frags + w/b once, then streams: wc loads (L2-hot) -> MFMA ->
// per-wave LDS transpose stage -> row-contiguous 1KB f32x4 stores.
// NO __syncthreads, no cross-wave deps; grid = 1024 blocks = 4/CU, all resident.
__global__ __launch_bounds__(256) void memconv_stream(
        const __bf16* __restrict__ wc,
        const __bf16* __restrict__ att_g,
        const float* __restrict__ wb,      // = out + BB*LL (w at 0, b at +BB)
        float* __restrict__ out) {
    __shared__ float stage[4][16 * 72];    // per-wave D staging

    const int lane = threadIdx.x & 63;
    const int wid  = threadIdx.x >> 6;
    const int cg   = lane & 15;
    const int kg   = lane >> 4;
    const int rg   = wid & 1;
    const int nh   = wid >> 1;
    const int r0   = blockIdx.x * 32 + rg * 16;
    const int n0   = nh * 512;

    // B fragments: att rows r0..r0+15 (bf16, stride 64, zero-padded k>=50)
    bf16x8 bfr0 = *(const bf16x8*)(att_g + (size_t)(r0 + cg) * 64 + kg * 8);
    bf16x8 bfr1 = *(const bf16x8*)(att_g + (size_t)(r0 + cg) * 64 + 32 + kg * 8);

    // w/b per output row, distributed via shfl (lane s<16 holds row r0+s)
    float w_reg = wb[r0 + cg];
    float b_reg = wb[BB + r0 + cg];
    float wj[4], bj[4];
    #pragma unroll
    for (int j = 0; j < 4; ++j) {
        wj[j] = __shfl(w_reg, j * 4 + kg);   // row j*4+kg
        bj[j] = __shfl(b_reg, j * 4 + kg);
    }

    float* st = stage[wid];
    #pragma unroll 2
    for (int R = 0; R < 8; ++R) {
        // compute 4 tiles (64 n-columns), stage D into this wave's LDS slot
        #pragma unroll
        for (int t = 0; t < 4; ++t) {
            int n = n0 + R * 64 + t * 16 + cg;
            bf16x8 a0 = *(const bf16x8*)(wc + n * 64 + kg * 8);
            bf16x8 a1 = *(const bf16x8*)(wc + n * 64 + 32 + kg * 8);
            f32x4 acc = {0.f, 0.f, 0.f, 0.f};
            acc = __builtin_amdgcn_mfma_f32_16x16x32_bf16(a0, bfr0, acc, 0, 0, 0);
            acc = __builtin_amdgcn_mfma_f32_16x16x32_bf16(a1, bfr1, acc, 0, 0, 0);
            *(f32x4*)(st + cg * 72 + t * 16 + kg * 4) = acc;
        }
        // flush: 4 insts, each 1KB = 4x 256B row-contiguous segments
        #pragma unroll
        for (int j = 0; j < 4; ++j) {
            int row = j * 4 + kg;
            int nl  = cg * 4;
            f32x4 v = *(const f32x4*)(st + row * 72 + nl);
            f32x4 o;
            #pragma unroll
            for (int k = 0; k < 4; ++k) o[k] = v[k] * wj[j] + bj[j];
            *(f32x4*)(out + (size_t)(r0 + row) * LL + n0 + R * 64 + nl) = o;
        }
    }
}

extern "C" void kernel_launch(void* const* d_in, const int* in_sizes, int n_in,
                              void* d_out, int out_size, void* d_ws, size_t ws_size,
                              hipStream_t stream) {
    const float* x     = (const float*)d_in[0];
    const float* dv    = (const float*)d_in[1];
    // d_in[2] = conv_w: DEAD CODE in the reference (st is overwritten by st_mem)
    const float* convt = (const float*)d_in[3];
    const float* memW  = (const float*)d_in[4];
    const float* dateW = (const float*)d_in[5];
    const float* fcww  = (const float*)d_in[6];
    const float* fcwb  = (const float*)d_in[7];
    const float* fcbw  = (const float*)d_in[8];
    const float* fcbb  = (const float*)d_in[9];
    float* out = (float*)d_out;
    __bf16* wc    = (__bf16*)d_ws;            // 65536 bf16 = 128 KB
    __bf16* att_g = (__bf16*)d_ws + 65536;    // 32768*64 bf16 = 4 MB

    prep_and_wb   <<<4352, 256, 0, stream>>>(convt, memW, x, fcww, fcwb, fcbw, fcbb,
                                             dv, dateW, wc, att_g, out);
    memconv_stream<<<BB / 32, 256, 0, stream>>>(wc, att_g, out + (size_t)BB * LL, out);
}

// Round 5
// 273.186 us; speedup vs baseline: 1.0735x; 1.0421x over previous
//
#include <hip/hip_runtime.h>
#include <hip/hip_bf16.h>

#define BB   32768
#define LL   1024
#define FEA  1028
#define MEM  50
#define DATE 32

typedef float  f32x4  __attribute__((ext_vector_type(4)));
typedef __bf16 bf16x8 __attribute__((ext_vector_type(8)));

// tanh via __expf: exact at both saturations, ~1e-6 abs error in between.
__device__ __forceinline__ float fast_tanh(float v) {
    float e = __expf(2.f * v);
    return 1.f - 2.f / (e + 1.f);
}

// wc[n*64+k] = sum_j convt_w[j] * mem_W[k][n+4-j], zero-padded k in [50,64)
__global__ __launch_bounds__(256) void prep_wc(
        const float* __restrict__ convt_w,
        const float* __restrict__ mem_W,
        __bf16* __restrict__ wc) {
    int idx = blockIdx.x * 256 + threadIdx.x;   // 65536
    int n = idx >> 6, k = idx & 63;
    float acc = 0.f;
    if (k < MEM) {
        #pragma unroll
        for (int j = 0; j < 5; ++j)
            acc += convt_w[j] * mem_W[k * FEA + n + 4 - j];
    }
    wc[n * 64 + k] = (__bf16)acc;
}

// Fused main kernel, chain-shortened:
//  - no softmax max-subtract (scores are O(0.3); softmax shift-invariant)
//  - butterfly reductions interleaved across rows (4-8 independent chains)
//  - fast_tanh instead of libm tanhf
//  - launch_bounds(256,2): 128 VGPR so x/fc loads are actually in flight
//  - x loads issued in 2 halves; first half before att so HBM hides under shfl
__global__ __launch_bounds__(256, 2) void memconv_fused2(
        const float* __restrict__ x,
        const float* __restrict__ dv,
        const float* __restrict__ dW,
        const float* __restrict__ fcw_w, const float* __restrict__ fcw_b,
        const float* __restrict__ fcb_w, const float* __restrict__ fcb_b,
        const __bf16* __restrict__ wc,
        float* __restrict__ out) {
    __shared__ __bf16 att_s[16 * 72];          // [row][k], 144B stride
    __shared__ float  w_s[16], b_s[16];
    __shared__ float  stage[4][16 * 72];       // per-wave D staging

    const int lane = threadIdx.x & 63;
    const int wid  = threadIdx.x >> 6;
    const int cg   = lane & 15;
    const int kg   = lane >> 4;
    const int b0   = blockIdx.x * 16;

    // ---- issue long-latency loads early: fc rows + first 2 x rows ----
    f32x4 wv[4], bv[4];
    #pragma unroll
    for (int c = 0; c < 4; ++c) {
        wv[c] = *(const f32x4*)(fcw_w + c * 256 + lane * 4);
        bv[c] = *(const f32x4*)(fcb_w + c * 256 + lane * 4);
    }
    f32x4 xv0[2][4];
    #pragma unroll
    for (int rr = 0; rr < 2; ++rr)
        #pragma unroll
        for (int c = 0; c < 4; ++c)
            xv0[rr][c] = *(const f32x4*)(x + (size_t)(b0 + wid * 4 + rr) * LL
                                           + c * 256 + lane * 4);

    // ---- att for rows wid*4..+3, overlapped with x loads ----
    {
        int m = lane < MEM ? lane : MEM - 1;
        float dwv[DATE];
        const f32x4* dwp = (const f32x4*)(dW + m * DATE);
        #pragma unroll
        for (int c = 0; c < 8; ++c) {
            f32x4 v = dwp[c];
            #pragma unroll
            for (int j = 0; j < 4; ++j) dwv[c * 4 + j] = v[j];
        }
        float e[4];
        #pragma unroll
        for (int rr = 0; rr < 4; ++rr) {
            const f32x4* dvp = (const f32x4*)(dv + (size_t)(b0 + wid * 4 + rr) * DATE);
            float sc = 0.f;
            #pragma unroll
            for (int c = 0; c < 8; ++c) {
                f32x4 v = dvp[c];
                #pragma unroll
                for (int j = 0; j < 4; ++j) sc += v[j] * dwv[c * 4 + j];
            }
            e[rr] = (lane < MEM) ? __expf(sc) : 0.f;   // no max-subtract
        }
        float s[4] = {e[0], e[1], e[2], e[3]};
        #pragma unroll
        for (int off = 32; off; off >>= 1) {
            #pragma unroll
            for (int rr = 0; rr < 4; ++rr) s[rr] += __shfl_xor(s[rr], off);
        }
        float p2[4];
        #pragma unroll
        for (int rr = 0; rr < 4; ++rr) {
            float p = e[rr] / s[rr];
            float d = p - 0.0025f;
            p2[rr]  = (d > 0.f) ? p * d / (d + 1e-12f) : 0.f;
        }
        float s2[4] = {p2[0], p2[1], p2[2], p2[3]};
        #pragma unroll
        for (int off = 32; off; off >>= 1) {
            #pragma unroll
            for (int rr = 0; rr < 4; ++rr) s2[rr] += __shfl_xor(s2[rr], off);
        }
        #pragma unroll
        for (int rr = 0; rr < 4; ++rr) {
            float att = p2[rr] / (s2[rr] + 1e-12f);
            att_s[(wid * 4 + rr) * 72 + lane] = (lane < MEM) ? (__bf16)att : (__bf16)0.f;
        }
    }

    // ---- second half of x rows ----
    f32x4 xv1[2][4];
    #pragma unroll
    for (int rr = 0; rr < 2; ++rr)
        #pragma unroll
        for (int c = 0; c < 4; ++c)
            xv1[rr][c] = *(const f32x4*)(x + (size_t)(b0 + wid * 4 + 2 + rr) * LL
                                           + c * 256 + lane * 4);

    // ---- GEMV for w/b: 8 interleaved butterfly chains, fast tanh ----
    {
        float aw[4], ab[4];
        #pragma unroll
        for (int rr = 0; rr < 2; ++rr) {
            float sa = 0.f, sb = 0.f;
            #pragma unroll
            for (int c = 0; c < 4; ++c)
                #pragma unroll
                for (int j = 0; j < 4; ++j) {
                    sa += xv0[rr][c][j] * wv[c][j];
                    sb += xv0[rr][c][j] * bv[c][j];
                }
            aw[rr] = sa; ab[rr] = sb;
        }
        #pragma unroll
        for (int rr = 0; rr < 2; ++rr) {
            float sa = 0.f, sb = 0.f;
            #pragma unroll
            for (int c = 0; c < 4; ++c)
                #pragma unroll
                for (int j = 0; j < 4; ++j) {
                    sa += xv1[rr][c][j] * wv[c][j];
                    sb += xv1[rr][c][j] * bv[c][j];
                }
            aw[2 + rr] = sa; ab[2 + rr] = sb;
        }
        #pragma unroll
        for (int off = 1; off <= 32; off <<= 1) {
            #pragma unroll
            for (int rr = 0; rr < 4; ++rr) {
                aw[rr] += __shfl_xor(aw[rr], off);
                ab[rr] += __shfl_xor(ab[rr], off);
            }
        }
        if (lane == 0) {
            float fwb = fcw_b[0], fbb = fcb_b[0];
            #pragma unroll
            for (int rr = 0; rr < 4; ++rr) {
                int r = wid * 4 + rr;
                float w  = fast_tanh(aw[rr] + fwb) * 0.5f + 1.0f;
                float bi = fast_tanh(ab[rr] + fbb) * 0.5f;
                w_s[r] = w; b_s[r] = bi;
                out[(size_t)BB * LL + (b0 + r)]      = w;
                out[(size_t)BB * LL + BB + (b0 + r)] = bi;
            }
        }
    }
    __syncthreads();

    // ---- Phase B: transposed-operand MFMA + LDS-staged contiguous stores ----
    // A = wc (m = n-dim), B = att (col = batch). D[n kg*4+j][batch cg].
    {
        bf16x8 bfr0 = *(const bf16x8*)(att_s + cg * 72 + kg * 8);
        bf16x8 bfr1 = *(const bf16x8*)(att_s + cg * 72 + 32 + kg * 8);
        float* st = stage[wid];
        const int n0 = wid * 256;
        #pragma unroll
        for (int R = 0; R < 4; ++R) {
            // compute 4 tiles (64 n-columns), stage D into LDS
            #pragma unroll
            for (int t = 0; t < 4; ++t) {
                int n = n0 + (R * 4 + t) * 16 + cg;
                bf16x8 a0 = *(const bf16x8*)(wc + n * 64 + kg * 8);
                bf16x8 a1 = *(const bf16x8*)(wc + n * 64 + 32 + kg * 8);
                f32x4 acc = {0.f, 0.f, 0.f, 0.f};
                acc = __builtin_amdgcn_mfma_f32_16x16x32_bf16(a0, bfr0, acc, 0, 0, 0);
                acc = __builtin_amdgcn_mfma_f32_16x16x32_bf16(a1, bfr1, acc, 0, 0, 0);
                *(f32x4*)(st + cg * 72 + t * 16 + kg * 4) = acc;
            }
            // flush: row-contiguous, 4x 256B segments per inst
            #pragma unroll
            for (int j = 0; j < 4; ++j) {
                int row = j * 4 + (lane >> 4);
                int nl  = (lane & 15) * 4;
                f32x4 v = *(const f32x4*)(st + row * 72 + nl);
                float w = w_s[row], bi = b_s[row];
                f32x4 o;
                #pragma unroll
                for (int k = 0; k < 4; ++k) o[k] = v[k] * w + bi;
                *(f32x4*)(out + (size_t)(b0 + row) * LL + n0 + R * 64 + nl) = o;
            }
        }
    }
}

extern "C" void kernel_launch(void* const* d_in, const int* in_sizes, int n_in,
                              void* d_out, int out_size, void* d_ws, size_t ws_size,
                              hipStream_t stream) {
    const float* x     = (const float*)d_in[0];
    const float* dv    = (const float*)d_in[1];
    // d_in[2] = conv_w: DEAD CODE in the reference (st is overwritten by st_mem)
    const float* convt = (const float*)d_in[3];
    const float* memW  = (const float*)d_in[4];
    const float* dateW = (const float*)d_in[5];
    const float* fcww  = (const float*)d_in[6];
    const float* fcwb  = (const float*)d_in[7];
    const float* fcbw  = (const float*)d_in[8];
    const float* fcbb  = (const float*)d_in[9];
    float* out = (float*)d_out;
    __bf16* wc = (__bf16*)d_ws;   // 64K bf16 = 128 KB

    prep_wc       <<<256,     256, 0, stream>>>(convt, memW, wc);
    memconv_fused2<<<BB / 16, 256, 0, stream>>>(x, dv, dateW, fcww, fcwb, fcbw, fcbb, wc, out);
}